// Round 1
// baseline (105.193 us; speedup 1.0000x reference)
//
#include <hip/hip_runtime.h>
#include <math.h>

// Problem constants: B=1, H=8, S=512, D=64, P=32
#define HH 8
#define SS 512
#define DD 64
#define PP 32

// NOTE (journal):
//  R5-R8: keep ICNN weights TRANSPOSED in LDS ([in][out], pad 68); do NOT fuse
//    weight prep into token kernel; no min-waves launch-bounds (R4: (256,4)
//    forced VGPR=64, 575 MB scratch spill).
//  R9 THEORY CORRECTION: the "81 us fixed poison-fill overhead" claim is
//    inconsistent with counters: csm_token3's 65 us window shows only 3.8 MB
//    of chip-wide TCC traffic -> no concurrent 256 MB fill. token3's 65 us is
//    real standalone latency-bound time (all pipes <13% busy, occupancy 10%,
//    1.5 blocks/CU, 4 barrier-drained phases). This round: 768 blocks x 16
//    tokens, upfront W1+W2 staging (one vmcnt drain), z1 via separate buffer
//    (4 barriers -> 2), shuffle-based fq/gk reduce, reduceM 32 -> 128 blocks.

__device__ __forceinline__ float softplusf(float x) {
    if (x > 20.f) return x;
    return log1pf(__expf(x));
}

// ---------------------------------------------------------------------------
// Kernel 0: one-time weight prep (softplus + transpose into wbuf).
//   [0..4096)      w1qT   [4096..8192)   w2qT
//   [8192..12288)  w1kT   [12288..16384) w2kT
//   [16384..18432) whT    [18432..20480) wvT
// ---------------------------------------------------------------------------
__global__ __launch_bounds__(256) void csm_prep(
    const float* __restrict__ sq1, const float* __restrict__ sq2,
    const float* __restrict__ sk1, const float* __restrict__ sk2,
    const float* __restrict__ Wh, const float* __restrict__ Wv,
    float* __restrict__ wbuf)
{
    int idx = blockIdx.x * 256 + threadIdx.x;   // grid = 80 blocks -> 20480
    if (idx < 16384) {
        int m = idx >> 12, r = idx & 4095;
        int i = r >> 6, j = r & 63;             // dest [i][j] = softplus(src[j][i])
        const float* src = (m == 0) ? sq1 : (m == 1) ? sq2 : (m == 2) ? sk1 : sk2;
        wbuf[idx] = softplusf(src[j * 64 + i]);
    } else if (idx < 18432) {
        int r = idx - 16384; int i = r >> 5, p = r & 31;
        wbuf[idx] = Wh[p * 64 + i];
    } else if (idx < 20480) {
        int r = idx - 18432; int i = r >> 5, p = r & 31;
        wbuf[idx] = Wv[p * 64 + i];
    }
}

// ---------------------------------------------------------------------------
// Kernel 1: per-token compute. 16 tokens/block -> 768 blocks.
// role = bx>>8: 0=q (fq, phiq), 1=k (gk, phik), 2=v (uexp).
// 256 threads = 16 tokens x 16 lanes; thread tile = 1 token x 4 outputs
// (x2 p for phi). W1, W2, Wh all staged upfront (53.2 KB LDS, 3 blocks/CU).
// ---------------------------------------------------------------------------
__global__ __launch_bounds__(256) void csm_token4(
    const float* __restrict__ q, const float* __restrict__ k, const float* __restrict__ v,
    const float* __restrict__ sq_b1, const float* __restrict__ sq_b2,
    const float* __restrict__ sk_b1, const float* __restrict__ sk_b2,
    const float* __restrict__ wbuf,
    float* __restrict__ fq, float* __restrict__ gk,
    float* __restrict__ phiq, float* __restrict__ phik, float* __restrict__ uexp)
{
    __shared__ float xs [16 * 68];    // X tile
    __shared__ float z1s[16 * 68];    // layer-1 activations (no xs overwrite)
    __shared__ float wb1[64 * 68];    // W1T
    __shared__ float wb2[64 * 68];    // W2T
    __shared__ float wh [64 * 36];    // WhT / WvT
    __shared__ float bb1[64], bb2[64];

    const int bx   = blockIdx.x;
    const int role = bx >> 8;
    const int sub  = bx & 255;
    const int g0   = sub * 16;        // first global token of this block
    const int tid  = threadIdx.x;
    const int m0   = tid >> 4;        // token 0..15
    const int tc   = tid & 15;
    const int n0   = tc * 4;          // ICNN output quad
    const int p0   = tc * 2;          // phi output pair

    const float* xin = (role == 0) ? q : (role == 1) ? k : v;

    // ---- stage X (16x64): one float4 per thread ----
    {
        const float4* xsrc = (const float4*)(xin + g0 * 64);
        *(float4*)&xs[m0 * 68 + tc * 4] = xsrc[tid];
    }
    // ---- stage projection weights (64x32 transposed [i][p]) ----
    {
        const float4* whsrc = (const float4*)(wbuf + ((role == 2) ? 18432 : 16384));
        #pragma unroll
        for (int c = 0; c < 2; ++c) {
            int idx4 = tid + c * 256;
            int i = idx4 >> 3, pc = (idx4 & 7) * 4;
            *(float4*)&wh[i * 36 + pc] = whsrc[idx4];
        }
    }
    if (role < 2) {
        // ---- stage BOTH ICNN layers upfront: one latency round trip ----
        const float4* w1src = (const float4*)(wbuf + (role == 0 ? 0 : 8192));
        const float4* w2src = (const float4*)(wbuf + (role == 0 ? 4096 : 12288));
        #pragma unroll
        for (int c = 0; c < 4; ++c) {
            int idx4 = tid + c * 256;
            int i = idx4 >> 4, jc = (idx4 & 15) * 4;
            *(float4*)&wb1[i * 68 + jc] = w1src[idx4];
            *(float4*)&wb2[i * 68 + jc] = w2src[idx4];
        }
        if (tid < 64)       bb1[tid]      = (role == 0 ? sq_b1 : sk_b1)[tid];
        else if (tid < 128) bb2[tid - 64] = (role == 0 ? sq_b2 : sk_b2)[tid - 64];
    }
    __syncthreads();

    if (role == 2) {
        float a0 = 0.f, a1 = 0.f;
        #pragma unroll
        for (int kc = 0; kc < 16; ++kc) {
            const int i0 = kc * 4;
            float4 xv = *(const float4*)&xs[m0 * 68 + i0];
            const float* xa = (const float*)&xv;
            #pragma unroll
            for (int kk = 0; kk < 4; ++kk) {
                float2 hv = *(const float2*)&wh[(i0 + kk) * 36 + p0];
                a0 += xa[kk] * hv.x;
                a1 += xa[kk] * hv.y;
            }
        }
        float2 o; o.x = __expf(a0); o.y = __expf(a1);
        *(float2*)&uexp[(g0 + m0) * 32 + p0] = o;
        return;   // divergence only at block granularity
    }

    // ---- layer 1 + phi fused ----
    float4 acc = *(const float4*)&bb1[n0];
    float ap0 = 0.f, ap1 = 0.f;
    #pragma unroll
    for (int kc = 0; kc < 16; ++kc) {
        const int i0 = kc * 4;
        float4 xv = *(const float4*)&xs[m0 * 68 + i0];
        const float* xa = (const float*)&xv;
        #pragma unroll
        for (int kk = 0; kk < 4; ++kk) {
            float4 wv = *(const float4*)&wb1[(i0 + kk) * 68 + n0];
            float2 hv = *(const float2*)&wh[(i0 + kk) * 36 + p0];
            const float xk = xa[kk];
            acc.x += xk * wv.x; acc.y += xk * wv.y;
            acc.z += xk * wv.z; acc.w += xk * wv.w;
            ap0   += xk * hv.x; ap1   += xk * hv.y;
        }
    }
    {
        float* phiout = (role == 0) ? phiq : phik;
        float2 o; o.x = __expf(ap0); o.y = __expf(ap1);
        *(float2*)&phiout[(g0 + m0) * 32 + p0] = o;
    }
    {
        float4 z1;
        z1.x = softplusf(acc.x); z1.y = softplusf(acc.y);
        z1.z = softplusf(acc.z); z1.w = softplusf(acc.w);
        *(float4*)&z1s[m0 * 68 + n0] = z1;   // separate buffer: no hazard on xs
    }
    __syncthreads();

    // ---- layer 2 ----
    float4 a2 = *(const float4*)&bb2[n0];
    #pragma unroll
    for (int kc = 0; kc < 16; ++kc) {
        const int i0 = kc * 4;
        float4 xv = *(const float4*)&z1s[m0 * 68 + i0];
        const float* xa = (const float*)&xv;
        #pragma unroll
        for (int kk = 0; kk < 4; ++kk) {
            float4 wv = *(const float4*)&wb2[(i0 + kk) * 68 + n0];
            const float xk = xa[kk];
            a2.x += xk * wv.x; a2.y += xk * wv.y;
            a2.z += xk * wv.z; a2.w += xk * wv.w;
        }
    }
    // per-token sum over 16 lanes: lanes of one token are consecutive -> shfl
    float s = softplusf(a2.x) + softplusf(a2.y) + softplusf(a2.z) + softplusf(a2.w);
    s += __shfl_xor(s, 1);
    s += __shfl_xor(s, 2);
    s += __shfl_xor(s, 4);
    s += __shfl_xor(s, 8);
    if (tc == 0) {
        if (role == 0) fq[g0 + m0] = s;
        else           gk[g0 + m0] = s;
    }
}

// ---------------------------------------------------------------------------
// Kernel 2: partial factorized reduction. Grid = 128 (8 heads x 16 chunks
// of 32 t). G = exact per-head max computed directly from gk[512]
// (deterministic -> identical across all blocks of a head).
//   Mpart[bx][r][p] = sum_{t in chunk} phik[t,r] * exp(gk[t]-G) * uexp[t,p]
// ---------------------------------------------------------------------------
__global__ __launch_bounds__(256) void csm_reduceM(
    const float* __restrict__ gk,
    const float* __restrict__ phik, const float* __restrict__ uexp,
    float* __restrict__ Mpart, float* __restrict__ Gbuf)
{
    __shared__ float pk[32 * 36];
    __shared__ float wu[32 * 36];
    __shared__ float wls[32];
    __shared__ float gred[4];

    const int h     = blockIdx.x >> 4;
    const int chunk = blockIdx.x & 15;
    const int tid   = threadIdx.x;
    const int t0    = chunk * 32;

    // exact per-head max of gk (512 values, 2 per thread, wave+LDS reduce)
    float g = fmaxf(gk[h * SS + tid], gk[h * SS + 256 + tid]);
    #pragma unroll
    for (int off = 1; off < 64; off <<= 1) g = fmaxf(g, __shfl_xor(g, off));
    if ((tid & 63) == 0) gred[tid >> 6] = g;
    __syncthreads();
    const float G = fmaxf(fmaxf(gred[0], gred[1]), fmaxf(gred[2], gred[3]));
    if (chunk == 0 && tid == 0) Gbuf[h] = G;
    if (tid < 32) wls[tid] = __expf(gk[h * SS + t0 + tid] - G);

    // stage phik and raw uexp for this chunk (one float4 each per thread)
    {
        const float4* psrc = (const float4*)(phik + (h * SS + t0) * PP);
        const float4* usrc = (const float4*)(uexp + (h * SS + t0) * PP);
        int t = tid >> 3, pc = (tid & 7) * 4;
        *(float4*)&pk[t * 36 + pc] = psrc[tid];
        *(float4*)&wu[t * 36 + pc] = usrc[tid];
    }
    __syncthreads();

    const int r0 = ((tid >> 5) & 7) * 4, p = tid & 31;
    float m0_ = 0.f, m1_ = 0.f, m2_ = 0.f, m3_ = 0.f;
    #pragma unroll
    for (int t = 0; t < 32; ++t) {
        const float wup = wu[t * 36 + p] * wls[t];
        const float4 pv = *(const float4*)&pk[t * 36 + r0];
        m0_ += pv.x * wup;
        m1_ += pv.y * wup;
        m2_ += pv.z * wup;
        m3_ += pv.w * wup;
    }
    float* mp = Mpart + blockIdx.x * 1024;
    mp[(r0 + 0) * 32 + p] = m0_;
    mp[(r0 + 1) * 32 + p] = m1_;
    mp[(r0 + 2) * 32 + p] = m2_;
    mp[(r0 + 3) * 32 + p] = m3_;
}

// ---------------------------------------------------------------------------
// Kernel 3: output. Sums the 16 M-partials of its head, then
//   y[s,p] = log( phi_q[s] . M[:,p] ) + f_q[s] + G - log S
// Grid = 512 blocks x 256 threads; block = 8 consecutive tokens x 32 p.
// ---------------------------------------------------------------------------
__global__ __launch_bounds__(256) void csm_out(
    const float* __restrict__ fq, const float* __restrict__ phiq,
    const float* __restrict__ Mpart, const float* __restrict__ Gbuf,
    float* __restrict__ y)
{
    __shared__ float Ms[32 * 36];
    __shared__ float pqs[8 * 32];
    __shared__ float fqs[8];

    const int bx = blockIdx.x;
    const int s0 = bx * 8;           // global token index (h*512+s)
    const int h  = bx >> 6;
    const int tid = threadIdx.x;

    {
        const float* base = Mpart + h * 16 * 1024 + tid * 4;
        float4 s = *(const float4*)base;
        #pragma unroll
        for (int c = 1; c < 16; ++c) {
            float4 a = *(const float4*)(base + c * 1024);
            s.x += a.x; s.y += a.y; s.z += a.z; s.w += a.w;
        }
        *(float4*)&Ms[(tid >> 3) * 36 + (tid & 7) * 4] = s;
    }
    pqs[tid] = phiq[s0 * 32 + tid];
    if (tid < 8) fqs[tid] = fq[s0 + tid];
    __syncthreads();

    const int si = tid >> 5, p = tid & 31;
    float acc = 0.f;
    #pragma unroll
    for (int rc = 0; rc < 8; ++rc) {
        const float4 pq = *(const float4*)&pqs[si * 32 + rc * 4];
        acc += pq.x * Ms[(rc * 4 + 0) * 36 + p];
        acc += pq.y * Ms[(rc * 4 + 1) * 36 + p];
        acc += pq.z * Ms[(rc * 4 + 2) * 36 + p];
        acc += pq.w * Ms[(rc * 4 + 3) * 36 + p];
    }
    const float LOG_S = 6.2383246250395078f;   // log(512)
    y[(s0 + si) * 32 + p] = __logf(acc) + fqs[si] + Gbuf[h] - LOG_S;
}

extern "C" void kernel_launch(void* const* d_in, const int* in_sizes, int n_in,
                              void* d_out, int out_size, void* d_ws, size_t ws_size,
                              hipStream_t stream) {
    (void)in_sizes; (void)n_in; (void)out_size; (void)ws_size;
    const float* q       = (const float*)d_in[0];
    const float* k       = (const float*)d_in[1];
    const float* v       = (const float*)d_in[2];
    const float* sq_raw1 = (const float*)d_in[3];
    const float* sq_b1   = (const float*)d_in[4];
    const float* sq_raw2 = (const float*)d_in[5];
    const float* sq_b2   = (const float*)d_in[6];
    const float* sk_raw1 = (const float*)d_in[7];
    const float* sk_b1   = (const float*)d_in[8];
    const float* sk_raw2 = (const float*)d_in[9];
    const float* sk_b2   = (const float*)d_in[10];
    const float* Wh      = (const float*)d_in[11];
    const float* Wv      = (const float*)d_in[12];
    float* y = (float*)d_out;

    float* ws     = (float*)d_ws;
    float* wbuf   = ws;                  // 20480
    float* fq     = ws + 20480;          // 4096
    float* gk     = ws + 24576;          // 4096
    float* Gbuf   = ws + 28672;          // 8 (padded to 128)
    float* phiq   = ws + 28800;          // 131072
    float* phik   = ws + 159872;         // 131072
    float* uexp   = ws + 290944;         // 131072
    float* Mpart  = ws + 422016;         // 128 * 1024 = 131072

    csm_prep<<<80, 256, 0, stream>>>(sq_raw1, sq_raw2, sk_raw1, sk_raw2, Wh, Wv, wbuf);
    csm_token4<<<768, 256, 0, stream>>>(q, k, v, sq_b1, sq_b2, sk_b1, sk_b2,
                                        wbuf, fq, gk, phiq, phik, uexp);
    csm_reduceM<<<128, 256, 0, stream>>>(gk, phik, uexp, Mpart, Gbuf);
    csm_out<<<512, 256, 0, stream>>>(fq, phiq, Mpart, Gbuf, y);
}